// Round 4
// baseline (289.959 us; speedup 1.0000x reference)
//
#include <hip/hip_runtime.h>
#include <hip/hip_bf16.h>

typedef __attribute__((ext_vector_type(8))) short short8;
typedef __attribute__((ext_vector_type(4))) float floatx4;
typedef __attribute__((ext_vector_type(4))) unsigned int uintx4;

#define WAVE_TRI 32    // 2 m-tiles of 16 per wave
#define TILE_TRI 128   // 4 waves per block

// fast GELU: x * (1 - 1/(exp(2u)+1)), u = 0.79788456*(x + 0.044715 x^3)
__device__ __forceinline__ float gelu_fast(float x)
{
    float u = 0.7978845608f * x * (1.0f + 0.044715f * x * x);
    float e = __builtin_amdgcn_exp2f(2.885390082f * u);   // exp(2u)
    return x - x * __builtin_amdgcn_rcpf(e + 1.0f);
}

// fp32 -> bf16 conversion of f_edge (8 elems/thread)
__global__ __launch_bounds__(256)
void cvt_bf16(const float* __restrict__ src, unsigned short* __restrict__ dst, int n8)
{
    int i = blockIdx.x * 256 + threadIdx.x;
    if (i >= n8) return;
    const float* s = src + (size_t)i * 8;
    unsigned short tmp[8] __attribute__((aligned(16)));
#pragma unroll
    for (int j = 0; j < 8; ++j) {
        __hip_bfloat16 b = __float2bfloat16(s[j]);
        tmp[j] = *(unsigned short*)&b;
    }
    *(uintx4*)(dst + (size_t)i * 8) = *(const uintx4*)tmp;
}

// Build fragment-ordered bf16 W: frag f=(ko*8+nt), lane l: 8 elems
// W[ko*32 + quad*8 + j][nt*16 + col]  (matches verified round-2/3 LDS layout)
__global__ __launch_bounds__(256)
void cvt_wperm(const float* __restrict__ Wg, uintx4* __restrict__ wq)
{
    int g = blockIdx.x * 256 + threadIdx.x;   // 0..6143
    if (g >= 6144) return;
    int frag = g >> 6, lane = g & 63;
    int ko = frag >> 3, nt = frag & 7;
    int col = lane & 15, quad = lane >> 4;
    unsigned short tmp[8] __attribute__((aligned(16)));
#pragma unroll
    for (int j = 0; j < 8; ++j) {
        __hip_bfloat16 b = __float2bfloat16(Wg[(ko * 32 + quad * 8 + j) * 128 + nt * 16 + col]);
        tmp[j] = *(unsigned short*)&b;
    }
    wq[g] = *(const uintx4*)tmp;
}

// Histogram of dst
__global__ __launch_bounds__(256)
void count_dst(const int* __restrict__ tri, int* __restrict__ cnt, int T)
{
    int i = blockIdx.x * 256 + threadIdx.x;
    if (i < T) atomicAdd(&cnt[tri[i * 3 + 2]], 1);
}

// Exclusive scan, 3-kernel (1024-wide blocks + 256-wide top scan + add-back)
__global__ __launch_bounds__(1024)
void scan1(const int* __restrict__ cnt, int* __restrict__ base,
           int* __restrict__ bsum, int E)
{
    __shared__ int sd[1024];
    int tid = threadIdx.x, g = blockIdx.x * 1024 + tid;
    int v = (g < E) ? cnt[g] : 0;
    sd[tid] = v;
    __syncthreads();
#pragma unroll
    for (int off = 1; off < 1024; off <<= 1) {
        int t = (tid >= off) ? sd[tid - off] : 0;
        __syncthreads();
        sd[tid] += t;
        __syncthreads();
    }
    if (g < E) base[g] = sd[tid] - v;
    if (tid == 1023) bsum[blockIdx.x] = sd[tid];
}

__global__ __launch_bounds__(256)
void scan2(int* __restrict__ bsum, int nb)
{
    __shared__ int sd[256];
    int tid = threadIdx.x;
    int v = (tid < nb) ? bsum[tid] : 0;
    sd[tid] = v;
    __syncthreads();
#pragma unroll
    for (int off = 1; off < 256; off <<= 1) {
        int t = (tid >= off) ? sd[tid - off] : 0;
        __syncthreads();
        sd[tid] += t;
        __syncthreads();
    }
    if (tid < nb) bsum[tid] = sd[tid] - v;   // exclusive
}

__global__ __launch_bounds__(1024)
void scan3(int* __restrict__ base, const int* __restrict__ bsum, int E)
{
    int g = blockIdx.x * 1024 + threadIdx.x;
    if (g < E) base[g] += bsum[blockIdx.x];
}

// GEMM (T x 384) @ (384 x 128), gather A from bf16 f_edge, B frags direct from
// global Wperm (L1/L2-resident). Epilogue: bias+GELU, CSR slot via
// atomicAdd(&base[dst],1), store permuted bf16 row at ht[slot].
// No LDS, no barriers; 2 m-tiles/wave -> ~100 regs -> 16 waves/CU.
__global__ __launch_bounds__(256, 4)
void tri_gemm(const unsigned short* __restrict__ fe,   // bf16 bits, E*128
              const uintx4* __restrict__ wq,           // fragment-ordered bf16 W
              const float* __restrict__ bias,          // fp32, 128
              const int* __restrict__ tri,             // T*3 int32
              int* __restrict__ base,                  // CSR cursors (mutated!)
              unsigned short* __restrict__ ht,         // bf16 bits, T*128 (CSR order)
              int T)
{
    const int tid  = threadIdx.x;
    const int wv   = tid >> 6;
    const int lane = tid & 63;
    const int col  = lane & 15;
    const int quad = lane >> 4;
    const int tb   = blockIdx.x * TILE_TRI + wv * WAVE_TRI;

    unsigned int offs[2][3];
#pragma unroll
    for (int mi = 0; mi < 2; ++mi) {
        int t  = tb + mi * 16 + col;
        int tc = t < T ? t : 0;
        offs[mi][0] = (unsigned)tri[tc * 3 + 0] * 256u;
        offs[mi][1] = (unsigned)tri[tc * 3 + 1] * 256u;
        offs[mi][2] = (unsigned)tri[tc * 3 + 2] * 256u;
    }
    const char* feb = (const char*)fe;

    floatx4 acc[2][8];
#pragma unroll
    for (int mi = 0; mi < 2; ++mi)
#pragma unroll
        for (int nt = 0; nt < 8; ++nt) acc[mi][nt] = (floatx4)0.0f;

#pragma unroll
    for (int ko = 0; ko < 12; ++ko) {
        int sgi = ko >> 2;
        int o   = ((ko & 3) << 6) + (quad << 4);
        short8 a0 = *(const short8*)(feb + offs[0][sgi] + o);
        short8 a1 = *(const short8*)(feb + offs[1][sgi] + o);
#pragma unroll
        for (int nt = 0; nt < 8; ++nt) {
            short8 bf = *(const short8*)&wq[(ko * 8 + nt) * 64 + lane];
            acc[0][nt] = __builtin_amdgcn_mfma_f32_16x16x32_bf16(a0, bf, acc[0][nt], 0, 0, 0);
            acc[1][nt] = __builtin_amdgcn_mfma_f32_16x16x32_bf16(a1, bf, acc[1][nt], 0, 0, 0);
        }
    }

    float bv[8];
#pragma unroll
    for (int nt = 0; nt < 8; ++nt) bv[nt] = bias[nt * 16 + col];

#pragma unroll
    for (int mi = 0; mi < 2; ++mi) {
#pragma unroll
        for (int r = 0; r < 4; ++r) {
            int t = tb + mi * 16 + quad * 4 + r;   // D row = quad*4 + reg
            if (t < T) {
                int p = 0;
                if (col == 0) p = atomicAdd(&base[tri[t * 3 + 2]], 1);
                p = __shfl(p, lane & 48);          // broadcast from quad's lane 0
                unsigned short pk[8] __attribute__((aligned(16)));
#pragma unroll
                for (int nt = 0; nt < 8; ++nt) {
                    float h = gelu_fast(acc[mi][nt][r] + bv[nt]);
                    __hip_bfloat16 hb = __float2bfloat16(h);
                    pk[nt] = *(unsigned short*)&hb;
                }
                *(uintx4*)(ht + (size_t)p * 128 + col * 8) = *(const uintx4*)pk;
            }
        }
    }
}

// Per-edge mean + LayerNorm over contiguous CSR runs. After tri_gemm,
// base[d] = end of segment d; start = base[d]-cnt[d]. Lane reads one bf16x2
// (4B) of each 256B permuted row -> fully coalesced streaming.
__global__ __launch_bounds__(256)
void mean_ln(const unsigned short* __restrict__ ht,
             const int* __restrict__ base, const int* __restrict__ cnt,
             const float* __restrict__ gamma, const float* __restrict__ beta,
             float* __restrict__ out, int E)
{
    int lane = threadIdx.x & 63;
    int row  = blockIdx.x * 4 + (threadIdx.x >> 6);
    if (row >= E) return;
    int col = lane & 15, q = lane >> 4;
    const char* htb = (const char*)ht;
    int boff = (col << 4) + (q << 2);   // byte offset within 256B row

    int e = base[row];
    int c = cnt[row];
    int s = e - c;
    float x0 = 0.0f, x1 = 0.0f;
    for (int i = s; i < e; ++i) {
        unsigned int w = *(const unsigned int*)(htb + (size_t)i * 256 + boff);
        x0 += __uint_as_float(w << 16);          // logical col j0 = 32q+col
        x1 += __uint_as_float(w & 0xffff0000u);  // logical col j1 = j0+16
    }
    float inv = 1.0f / fmaxf((float)c, 1.0f);
    float m0 = x0 * inv, m1 = x1 * inv;
    float sm = m0 + m1;
#pragma unroll
    for (int o = 32; o > 0; o >>= 1) sm += __shfl_xor(sm, o);
    float mu = sm * (1.0f / 128.0f);
    float d0 = m0 - mu, d1 = m1 - mu;
    float v = d0 * d0 + d1 * d1;
#pragma unroll
    for (int o = 32; o > 0; o >>= 1) v += __shfl_xor(v, o);
    float rstd = rsqrtf(v * (1.0f / 128.0f) + 1e-5f);
    int j0 = q * 32 + col, j1 = j0 + 16;
    out[(size_t)row * 128 + j0] = d0 * rstd * gamma[j0] + beta[j0];
    out[(size_t)row * 128 + j1] = d1 * rstd * gamma[j1] + beta[j1];
}

extern "C" void kernel_launch(void* const* d_in, const int* in_sizes, int n_in,
                              void* d_out, int out_size, void* d_ws, size_t ws_size,
                              hipStream_t stream)
{
    const float* fe_f  = (const float*)d_in[0];
    const float* Wg    = (const float*)d_in[1];
    const float* bias  = (const float*)d_in[2];
    const float* gamma = (const float*)d_in[3];
    const float* beta  = (const float*)d_in[4];
    const int*   tri   = (const int*)d_in[5];

    int E = in_sizes[0] / 128;
    int T = in_sizes[5] / 3;

    // ws: ht (T*128 bf16) | febf (E*128 bf16) | Wperm (96KB) | cnt (E i32) |
    //     base (E i32) | bsum (1024 i32)
    unsigned short* ht   = (unsigned short*)d_ws;
    unsigned short* febf = ht + (size_t)T * 128;
    uintx4* wq = (uintx4*)(febf + (size_t)E * 128);
    int* cnt  = (int*)((char*)wq + 6144 * 16);
    int* base = cnt + E;
    int* bsum = base + E;

    hipMemsetAsync(cnt, 0, (size_t)E * sizeof(int), stream);

    int n8 = E * 128 / 8;
    cvt_bf16<<<(n8 + 255) / 256, 256, 0, stream>>>(fe_f, febf, n8);
    cvt_wperm<<<24, 256, 0, stream>>>(Wg, wq);
    count_dst<<<(T + 255) / 256, 256, 0, stream>>>(tri, cnt, T);

    int nb = (E + 1023) / 1024;
    scan1<<<nb, 1024, 0, stream>>>(cnt, base, bsum, E);
    scan2<<<1, 256, 0, stream>>>(bsum, nb);
    scan3<<<nb, 1024, 0, stream>>>(base, bsum, E);

    tri_gemm<<<(T + TILE_TRI - 1) / TILE_TRI, 256, 0, stream>>>(
        febf, wq, bias, tri, base, ht, T);

    mean_ln<<<(E + 3) / 4, 256, 0, stream>>>(ht, base, cnt, gamma, beta,
                                             (float*)d_out, E);
}